// Round 2
// baseline (357.038 us; speedup 1.0000x reference)
//
#include <hip/hip_runtime.h>

#define NUM_CODES 512
#define CODE_DIM 64
#define N_ROWS (32 * 4096)
#define KU 4  // codes processed concurrently (independent FMA chains)

__global__ void vq_precompute_c2(const float* __restrict__ cb,
                                 float* __restrict__ c2) {
    int k = blockIdx.x * blockDim.x + threadIdx.x;
    if (k < NUM_CODES) {
        const float* c = cb + (size_t)k * CODE_DIM;
        float s = 0.f;
#pragma unroll
        for (int d = 0; d < CODE_DIM; ++d) s = fmaf(c[d], c[d], s);
        c2[k] = s;
    }
}

__global__ __launch_bounds__(256) void vq_main(
    const float* __restrict__ latents, const float* __restrict__ cb,
    const float* __restrict__ c2, float* __restrict__ out_q,
    float* __restrict__ out_codes, float* __restrict__ loss_accum) {
    const int row = blockIdx.x * blockDim.x + threadIdx.x;  // grid sized exactly
    const float* __restrict__ x = latents + (size_t)row * CODE_DIM;

    // Row into registers (16 x float4 = 64 VGPRs)
    float xv[CODE_DIM];
#pragma unroll
    for (int i = 0; i < CODE_DIM / 4; ++i) {
        float4 v = reinterpret_cast<const float4*>(x)[i];
        xv[4 * i + 0] = v.x;
        xv[4 * i + 1] = v.y;
        xv[4 * i + 2] = v.z;
        xv[4 * i + 3] = v.w;
    }

    // x2 = sum(x*x), matching the reference's separate x2 term
    float x2 = 0.f;
#pragma unroll
    for (int d = 0; d < CODE_DIM; ++d) x2 = fmaf(xv[d], xv[d], x2);

    // Reference formula per code: dist = (x2 - 2*xc) + c2[k].
    // 2*s is exact (power-of-2 scale), so (x2 - 2*s) rounds identically to the
    // reference's x2 - 2.0*xc. Strict '<' ascending k == jnp.argmin tie-break.
    float bestd = __builtin_inff();
    int bk = 0;
    for (int k0 = 0; k0 < NUM_CODES; k0 += KU) {
        const float* __restrict__ c = cb + (size_t)k0 * CODE_DIM;  // wave-uniform
        float s0 = 0.f, s1 = 0.f, s2 = 0.f, s3 = 0.f;
#pragma unroll
        for (int d = 0; d < CODE_DIM; ++d) {
            s0 = fmaf(xv[d], c[d + 0 * CODE_DIM], s0);
            s1 = fmaf(xv[d], c[d + 1 * CODE_DIM], s1);
            s2 = fmaf(xv[d], c[d + 2 * CODE_DIM], s2);
            s3 = fmaf(xv[d], c[d + 3 * CODE_DIM], s3);
        }
        float d0 = (x2 - 2.0f * s0) + c2[k0 + 0];
        float d1 = (x2 - 2.0f * s1) + c2[k0 + 1];
        float d2 = (x2 - 2.0f * s2) + c2[k0 + 2];
        float d3 = (x2 - 2.0f * s3) + c2[k0 + 3];
        if (d0 < bestd) { bestd = d0; bk = k0 + 0; }
        if (d1 < bestd) { bestd = d1; bk = k0 + 1; }
        if (d2 < bestd) { bestd = d2; bk = k0 + 2; }
        if (d3 < bestd) { bestd = d3; bk = k0 + 3; }
    }

    // Gather winning code, write straight-through output + per-thread loss partial
    const float* __restrict__ q = cb + (size_t)bk * CODE_DIM;
    float4* oq = reinterpret_cast<float4*>(out_q + (size_t)row * CODE_DIM);
    float lsum = 0.f;
#pragma unroll
    for (int i = 0; i < CODE_DIM / 4; ++i) {
        float4 qq = reinterpret_cast<const float4*>(q)[i];
        float xx0 = xv[4 * i + 0], xx1 = xv[4 * i + 1];
        float xx2 = xv[4 * i + 2], xx3 = xv[4 * i + 3];
        // loss uses (x - q)
        float d0 = xx0 - qq.x, d1 = xx1 - qq.y, d2 = xx2 - qq.z, d3 = xx3 - qq.w;
        lsum = fmaf(d0, d0, lsum);
        lsum = fmaf(d1, d1, lsum);
        lsum = fmaf(d2, d2, lsum);
        lsum = fmaf(d3, d3, lsum);
        // straight-through: x + (q - x), same op order as reference
        float4 ov;
        ov.x = xx0 + (qq.x - xx0);
        ov.y = xx1 + (qq.y - xx1);
        ov.z = xx2 + (qq.z - xx2);
        ov.w = xx3 + (qq.w - xx3);
        oq[i] = ov;
    }
    out_codes[row] = (float)bk;

    // block-reduce loss partial: wave shfl + LDS across 4 waves + 1 atomic/block
#pragma unroll
    for (int off = 32; off > 0; off >>= 1) lsum += __shfl_down(lsum, off);
    __shared__ float red[4];
    int lane = threadIdx.x & 63;
    int wid = threadIdx.x >> 6;
    if (lane == 0) red[wid] = lsum;
    __syncthreads();
    if (threadIdx.x == 0) {
        float t = red[0] + red[1] + red[2] + red[3];
        atomicAdd(loss_accum, t);
    }
}

__global__ void vq_finalize(const float* __restrict__ acc,
                            float* __restrict__ out_loss) {
    // vq_loss = embedding_loss + 0.25*commitment_loss = 1.25 * MSE
    *out_loss = 1.25f * (*acc) / (float)(N_ROWS * CODE_DIM);
}

extern "C" void kernel_launch(void* const* d_in, const int* in_sizes, int n_in,
                              void* d_out, int out_size, void* d_ws, size_t ws_size,
                              hipStream_t stream) {
    const float* latents = (const float*)d_in[0];
    const float* cb      = (const float*)d_in[1];

    float* out_q     = (float*)d_out;            // 8388608 floats
    float* out_codes = out_q + (size_t)N_ROWS * CODE_DIM;  // 131072 floats
    float* out_loss  = out_codes + N_ROWS;       // 1 float

    float* c2  = (float*)d_ws;                   // 512 floats
    float* acc = c2 + NUM_CODES;                 // 1 float (loss accumulator)

    hipMemsetAsync(acc, 0, sizeof(float), stream);
    vq_precompute_c2<<<2, 256, 0, stream>>>(cb, c2);
    vq_main<<<N_ROWS / 256, 256, 0, stream>>>(latents, cb, c2, out_q, out_codes, acc);
    vq_finalize<<<1, 1, 0, stream>>>(acc, out_loss);
}

// Round 3
// 243.195 us; speedup vs baseline: 1.4681x; 1.4681x over previous
//
#include <hip/hip_runtime.h>

#define NUM_CODES 512
#define CODE_DIM 64
#define N_ROWS (32 * 4096)
#define ROWS_PER_BLOCK 64
#define WAVES_PER_BLOCK 4
#define CODES_PER_WAVE (NUM_CODES / WAVES_PER_BLOCK)  // 128
#define KU 4  // codes processed concurrently (independent FMA chains)

__global__ void vq_precompute_c2(const float* __restrict__ cb,
                                 float* __restrict__ c2) {
    int k = blockIdx.x * blockDim.x + threadIdx.x;
    if (k < NUM_CODES) {
        const float* c = cb + (size_t)k * CODE_DIM;
        float s = 0.f;
#pragma unroll
        for (int d = 0; d < CODE_DIM; ++d) s = fmaf(c[d], c[d], s);
        c2[k] = s;
    }
}

__global__ __launch_bounds__(256) void vq_main(
    const float* __restrict__ latents, const float* __restrict__ cb,
    const float* __restrict__ c2, float* __restrict__ out_q,
    float* __restrict__ out_codes, float* __restrict__ loss_accum) {
    const int lane = threadIdx.x & 63;
    const int wave = threadIdx.x >> 6;
    const int row = blockIdx.x * ROWS_PER_BLOCK + lane;
    // wave-uniform code-chunk base, forced into an SGPR so codebook loads scalarize
    const int chunk0 = __builtin_amdgcn_readfirstlane(wave) * CODES_PER_WAVE;

    const float* __restrict__ x = latents + (size_t)row * CODE_DIM;

    // Row into registers (16 x float4 = 64 VGPRs)
    float xv[CODE_DIM];
#pragma unroll
    for (int i = 0; i < CODE_DIM / 4; ++i) {
        float4 v = reinterpret_cast<const float4*>(x)[i];
        xv[4 * i + 0] = v.x;
        xv[4 * i + 1] = v.y;
        xv[4 * i + 2] = v.z;
        xv[4 * i + 3] = v.w;
    }

    // x2 = sum(x*x), matching the reference's separate x2 term
    float x2 = 0.f;
#pragma unroll
    for (int d = 0; d < CODE_DIM; ++d) x2 = fmaf(xv[d], xv[d], x2);

    // Reference formula per code: dist = (x2 - 2*xc) + c2[k].
    // 2*s is exact (power-of-2 scale), so (x2 - 2*s) rounds identically to the
    // reference. Strict '<' ascending k == jnp.argmin first-min tie-break.
    float bestd = __builtin_inff();
    int bk = 0;
    for (int kk = 0; kk < CODES_PER_WAVE; kk += KU) {
        const int k0 = chunk0 + kk;
        const float* __restrict__ c = cb + (size_t)k0 * CODE_DIM;  // wave-uniform
        float s0 = 0.f, s1 = 0.f, s2 = 0.f, s3 = 0.f;
#pragma unroll
        for (int d = 0; d < CODE_DIM; ++d) {
            s0 = fmaf(xv[d], c[d + 0 * CODE_DIM], s0);
            s1 = fmaf(xv[d], c[d + 1 * CODE_DIM], s1);
            s2 = fmaf(xv[d], c[d + 2 * CODE_DIM], s2);
            s3 = fmaf(xv[d], c[d + 3 * CODE_DIM], s3);
        }
        float d0 = (x2 - 2.0f * s0) + c2[k0 + 0];
        float d1 = (x2 - 2.0f * s1) + c2[k0 + 1];
        float d2 = (x2 - 2.0f * s2) + c2[k0 + 2];
        float d3 = (x2 - 2.0f * s3) + c2[k0 + 3];
        if (d0 < bestd) { bestd = d0; bk = k0 + 0; }
        if (d1 < bestd) { bestd = d1; bk = k0 + 1; }
        if (d2 < bestd) { bestd = d2; bk = k0 + 2; }
        if (d3 < bestd) { bestd = d3; bk = k0 + 3; }
    }

    // Cross-wave argmin combine: wave w covers code chunk w (ascending indices),
    // so strict '<' with ascending w keeps the lowest code index on exact ties.
    __shared__ float sdist[WAVES_PER_BLOCK][ROWS_PER_BLOCK];
    __shared__ int sidx[WAVES_PER_BLOCK][ROWS_PER_BLOCK];
    sdist[wave][lane] = bestd;
    sidx[wave][lane] = bk;
    __syncthreads();
    if (wave != 0) return;

    float bd = sdist[0][lane];
    int bi = sidx[0][lane];
#pragma unroll
    for (int w = 1; w < WAVES_PER_BLOCK; ++w) {
        float d = sdist[w][lane];
        int i = sidx[w][lane];
        if (d < bd) { bd = d; bi = i; }
    }

    // Gather winning code, write straight-through output + per-thread loss partial
    const float* __restrict__ q = cb + (size_t)bi * CODE_DIM;
    float4* oq = reinterpret_cast<float4*>(out_q + (size_t)row * CODE_DIM);
    float lsum = 0.f;
#pragma unroll
    for (int i = 0; i < CODE_DIM / 4; ++i) {
        float4 qq = reinterpret_cast<const float4*>(q)[i];
        float xx0 = xv[4 * i + 0], xx1 = xv[4 * i + 1];
        float xx2 = xv[4 * i + 2], xx3 = xv[4 * i + 3];
        float e0 = xx0 - qq.x, e1 = xx1 - qq.y, e2 = xx2 - qq.z, e3 = xx3 - qq.w;
        lsum = fmaf(e0, e0, lsum);
        lsum = fmaf(e1, e1, lsum);
        lsum = fmaf(e2, e2, lsum);
        lsum = fmaf(e3, e3, lsum);
        // straight-through: x + (q - x), same op order as reference
        float4 ov;
        ov.x = xx0 + (qq.x - xx0);
        ov.y = xx1 + (qq.y - xx1);
        ov.z = xx2 + (qq.z - xx2);
        ov.w = xx3 + (qq.w - xx3);
        oq[i] = ov;
    }
    out_codes[row] = (float)bi;

    // wave-level loss reduce + one atomic per block
#pragma unroll
    for (int off = 32; off > 0; off >>= 1) lsum += __shfl_down(lsum, off);
    if (lane == 0) atomicAdd(loss_accum, lsum);
}

__global__ void vq_finalize(const float* __restrict__ acc,
                            float* __restrict__ out_loss) {
    // vq_loss = embedding_loss + 0.25*commitment_loss = 1.25 * MSE
    *out_loss = 1.25f * (*acc) / (float)(N_ROWS * CODE_DIM);
}

extern "C" void kernel_launch(void* const* d_in, const int* in_sizes, int n_in,
                              void* d_out, int out_size, void* d_ws, size_t ws_size,
                              hipStream_t stream) {
    const float* latents = (const float*)d_in[0];
    const float* cb      = (const float*)d_in[1];

    float* out_q     = (float*)d_out;                      // 8388608 floats
    float* out_codes = out_q + (size_t)N_ROWS * CODE_DIM;  // 131072 floats
    float* out_loss  = out_codes + N_ROWS;                 // 1 float

    float* c2  = (float*)d_ws;                             // 512 floats
    float* acc = c2 + NUM_CODES;                           // 1 float

    hipMemsetAsync(acc, 0, sizeof(float), stream);
    vq_precompute_c2<<<2, 256, 0, stream>>>(cb, c2);
    vq_main<<<N_ROWS / ROWS_PER_BLOCK, 256, 0, stream>>>(latents, cb, c2, out_q,
                                                         out_codes, acc);
    vq_finalize<<<1, 1, 0, stream>>>(acc, out_loss);
}

// Round 7
// 227.475 us; speedup vs baseline: 1.5696x; 1.0691x over previous
//
#include <hip/hip_runtime.h>

#define NUM_CODES 512
#define CODE_DIM 64
#define N_ROWS (32 * 4096)
#define ROWS_PER_BLOCK 64
#define WAVES_PER_BLOCK 4
#define CODES_PER_WAVE (NUM_CODES / WAVES_PER_BLOCK)  // 128

typedef float f32x16 __attribute__((ext_vector_type(16)));

// Launder a wave-uniform pointer into the compiler's uniform (SGPR) domain.
static __device__ inline const float* uniform_ptr(const float* p) {
    uint64_t u = (uint64_t)p;
    uint32_t lo = __builtin_amdgcn_readfirstlane((uint32_t)u);
    uint32_t hi = __builtin_amdgcn_readfirstlane((uint32_t)(u >> 32));
    return (const float*)(((uint64_t)hi << 32) | lo);
}

__global__ void vq_precompute_c2(const float* __restrict__ cb,
                                 float* __restrict__ c2) {
    int k = blockIdx.x * blockDim.x + threadIdx.x;
    if (k < NUM_CODES) {
        const float* c = cb + (size_t)k * CODE_DIM;
        float s = 0.f;
#pragma unroll
        for (int d = 0; d < CODE_DIM; ++d) s = fmaf(c[d], c[d], s);
        c2[k] = s;
    }
}

__global__ __launch_bounds__(256, 4) void vq_main(
    const float* __restrict__ latents, const float* __restrict__ cb,
    const float* __restrict__ c2g, float* __restrict__ out_q,
    float* __restrict__ out_codes, float* __restrict__ loss_accum) {
    const int lane = threadIdx.x & 63;
    const int wave = threadIdx.x >> 6;
    const int row = blockIdx.x * ROWS_PER_BLOCK + lane;
    const int chunk0 = wave * CODES_PER_WAVE;

    // ---- x row resident in VGPRs (64 regs; 128-reg budget from launch_bounds) ----
    const float* __restrict__ x = latents + (size_t)row * CODE_DIM;
    float xv[CODE_DIM];
#pragma unroll
    for (int i = 0; i < CODE_DIM / 4; ++i) {
        float4 v = reinterpret_cast<const float4*>(x)[i];
        xv[4 * i + 0] = v.x;
        xv[4 * i + 1] = v.y;
        xv[4 * i + 2] = v.z;
        xv[4 * i + 3] = v.w;
    }
    float x2 = 0.f;
#pragma unroll
    for (int d = 0; d < CODE_DIM; ++d) x2 = fmaf(xv[d], xv[d], x2);

    // ---- scan this wave's 128-code chunk; codebook via scalar pipe (SGPRs) ----
    float bestd = __builtin_inff();
    int bk = 0;
    // readfirstlane: provably wave-uniform -> SGPR pair, satisfies "s" constraint
    const float* cp = uniform_ptr(cb + (size_t)chunk0 * CODE_DIM);
    const float* zp = uniform_ptr(c2g + chunk0);

#pragma unroll 1
    for (int k = 0; k < CODES_PER_WAVE; ++k) {
        f32x16 c0, c1, c2, c3;
        float zz;
        asm volatile("s_load_dwordx16 %0, %1, 0x00" : "=s"(c0) : "s"(cp));
        asm volatile("s_load_dwordx16 %0, %1, 0x40" : "=s"(c1) : "s"(cp));
        asm volatile("s_load_dwordx16 %0, %1, 0x80" : "=s"(c2) : "s"(cp));
        asm volatile("s_load_dwordx16 %0, %1, 0xc0" : "=s"(c3) : "s"(cp));
        asm volatile("s_load_dword %0, %1, 0x00" : "=s"(zz) : "s"(zp));
        // wait tied to all consumed SGPRs: consumers cannot hoist above it
        asm volatile("s_waitcnt lgkmcnt(0)"
                     : "+s"(c0), "+s"(c1), "+s"(c2), "+s"(c3), "+s"(zz));

        // single ascending-d chain: bit-exact vs reference dot accumulation
        float s = 0.f;
#pragma unroll
        for (int q = 0; q < 16; ++q) s = fmaf(xv[q], c0[q], s);
#pragma unroll
        for (int q = 0; q < 16; ++q) s = fmaf(xv[16 + q], c1[q], s);
#pragma unroll
        for (int q = 0; q < 16; ++q) s = fmaf(xv[32 + q], c2[q], s);
#pragma unroll
        for (int q = 0; q < 16; ++q) s = fmaf(xv[48 + q], c3[q], s);

        // reference formula order: (x2 - 2*xc) + c2[k]; strict '<' ascending k
        float dist = (x2 - 2.0f * s) + zz;
        if (dist < bestd) { bestd = dist; bk = chunk0 + k; }
        cp += CODE_DIM;
        zp += 1;
    }

    // ---- cross-wave argmin combine (ascending wave = ascending code chunks) ----
    __shared__ float sdist[WAVES_PER_BLOCK][ROWS_PER_BLOCK];
    __shared__ int sidx[WAVES_PER_BLOCK][ROWS_PER_BLOCK];
    __shared__ int sbi[ROWS_PER_BLOCK];
    sdist[wave][lane] = bestd;
    sidx[wave][lane] = bk;
    __syncthreads();
    if (wave == 0) {
        float bd = sdist[0][lane];
        int bi = sidx[0][lane];
#pragma unroll
        for (int w = 1; w < WAVES_PER_BLOCK; ++w) {
            float d = sdist[w][lane];
            int i = sidx[w][lane];
            if (d < bd) { bd = d; bi = i; }
        }
        sbi[lane] = bi;
    }
    __syncthreads();

    // ---- parallel epilogue: wave w writes rows [16w, 16w+16) ----
    float lsum = 0.f;
#pragma unroll
    for (int rr = 0; rr < 16; ++rr) {
        const int r = wave * 16 + rr;
        const size_t grow = (size_t)blockIdx.x * ROWS_PER_BLOCK + r;
        const int bi = sbi[r];  // wave-uniform broadcast
        float xd = latents[grow * CODE_DIM + lane];   // coalesced (L2/L3)
        float qd = cb[(size_t)bi * CODE_DIM + lane];  // coalesced
        float e = xd - qd;
        lsum = fmaf(e, e, lsum);
        out_q[grow * CODE_DIM + lane] = xd + (qd - xd);  // reference op order
        if (lane == 0) out_codes[grow] = (float)bi;
    }
#pragma unroll
    for (int off = 32; off > 0; off >>= 1) lsum += __shfl_down(lsum, off);
    __shared__ float red[WAVES_PER_BLOCK];
    if (lane == 0) red[wave] = lsum;
    __syncthreads();
    if (threadIdx.x == 0)
        atomicAdd(loss_accum, red[0] + red[1] + red[2] + red[3]);
}

__global__ void vq_finalize(const float* __restrict__ acc,
                            float* __restrict__ out_loss) {
    *out_loss = 1.25f * (*acc) / (float)(N_ROWS * CODE_DIM);
}

extern "C" void kernel_launch(void* const* d_in, const int* in_sizes, int n_in,
                              void* d_out, int out_size, void* d_ws, size_t ws_size,
                              hipStream_t stream) {
    const float* latents = (const float*)d_in[0];
    const float* cb      = (const float*)d_in[1];

    float* out_q     = (float*)d_out;                      // 8388608 floats
    float* out_codes = out_q + (size_t)N_ROWS * CODE_DIM;  // 131072 floats
    float* out_loss  = out_codes + N_ROWS;                 // 1 float

    float* c2  = (float*)d_ws;                             // 512 floats
    float* acc = c2 + NUM_CODES;                           // 1 float

    hipMemsetAsync(acc, 0, sizeof(float), stream);
    vq_precompute_c2<<<2, 256, 0, stream>>>(cb, c2);
    vq_main<<<N_ROWS / ROWS_PER_BLOCK, 256, 0, stream>>>(latents, cb, c2, out_q,
                                                         out_codes, acc);
    vq_finalize<<<1, 1, 0, stream>>>(acc, out_loss);
}

// Round 15
// 220.373 us; speedup vs baseline: 1.6202x; 1.0322x over previous
//
#include <hip/hip_runtime.h>

#define NUM_CODES 512
#define CODE_DIM 64
#define N_ROWS (32 * 4096)
#define RPB 32                   // rows per block
#define DC 8                     // dims per staged chunk
#define NCHUNK (CODE_DIM / DC)   // 8
#define CBLK 12                  // 8 codes + 4 pad floats -> 48B block stride

// ---- kernel 1: per-code c2 (ascending-d fmaf chain: bit-exact lineage) ----
__global__ void vq_prep(const float* __restrict__ cb, float* __restrict__ c2) {
    int k = blockIdx.x * 64 + threadIdx.x;
    const float* c = cb + (size_t)k * CODE_DIM;
    float s = 0.f;
#pragma unroll
    for (int d = 0; d < CODE_DIM; ++d) s = fmaf(c[d], c[d], s);
    c2[k] = s;
}

// ---- kernel 2: register-tiled distance GEMM + argmin + outputs ----
__global__ __launch_bounds__(256, 4) void vq_main(
    const float* __restrict__ latents, const float* __restrict__ cb,
    const float* __restrict__ c2g, float* __restrict__ out_q,
    float* __restrict__ out_codes, float* __restrict__ loss_accum) {
    const int tid = threadIdx.x;
    const int lane = tid & 63;
    const int wave = tid >> 6;
    const size_t R0 = (size_t)blockIdx.x * RPB;

    __shared__ float xT[CODE_DIM][RPB];      // 8 KB, [d][row]
    __shared__ float cT[DC][64][CBLK];       // 24 KB, padded: block b = codes 8b..8b+7
    __shared__ float c2s[NUM_CODES];         // 2 KB
    __shared__ float x2s[RPB];
    __shared__ int sbi[RPB];
    __shared__ float red[4];

    // stage x transposed: thread -> row tid>>3, dims (tid&7)*8..+7
    {
        int r = tid >> 3;
        int d0 = (tid & 7) * 8;
        const float* xp = latents + (R0 + r) * CODE_DIM + d0;
        float4 a = *(const float4*)(xp);
        float4 b = *(const float4*)(xp + 4);
        xT[d0 + 0][r] = a.x; xT[d0 + 1][r] = a.y;
        xT[d0 + 2][r] = a.z; xT[d0 + 3][r] = a.w;
        xT[d0 + 4][r] = b.x; xT[d0 + 5][r] = b.y;
        xT[d0 + 6][r] = b.z; xT[d0 + 7][r] = b.w;
    }
    if (tid < NUM_CODES / 4)  // stage c2 (128 float4s)
        ((float4*)c2s)[tid] = ((const float4*)c2g)[tid];
    __syncthreads();

    // x2 per row: serial ascending-d fmaf chain (bit-exact lineage, R3/R7).
    // Wave w writes xT rows 8w..8w+7 and computes x2s for those same rows:
    // same-wave DS ordering, no extra barrier needed.
    if (lane < 8) {
        int r = wave * 8 + lane;
        float s = 0.f;
#pragma unroll
        for (int d = 0; d < CODE_DIM; ++d) s = fmaf(xT[d][r], xT[d][r], s);
        x2s[r] = s;
    }

    float acc[8][8];
#pragma unroll
    for (int r = 0; r < 8; ++r)
#pragma unroll
        for (int k = 0; k < 8; ++k) acc[r][k] = 0.f;

#pragma unroll 1
    for (int ch = 0; ch < NCHUNK; ++ch) {
        // stage chunk transposed directly from row-major cb (L2-resident):
        // thread covers code c = p*256+tid, dims ch*8..+8 (16B reads, 256B lane
        // stride -> L2-hot). LDS writes: 48B block stride -> 2 lanes/bank (free).
#pragma unroll
        for (int p = 0; p < 2; ++p) {
            int c = p * 256 + tid;
            const float* gp = cb + (size_t)c * CODE_DIM + ch * DC;
            float4 a = *(const float4*)(gp);
            float4 b = *(const float4*)(gp + 4);
            int blk = c >> 3, e = c & 7;
            cT[0][blk][e] = a.x; cT[1][blk][e] = a.y;
            cT[2][blk][e] = a.z; cT[3][blk][e] = a.w;
            cT[4][blk][e] = b.x; cT[5][blk][e] = b.y;
            cT[6][blk][e] = b.z; cT[7][blk][e] = b.w;
        }
        __syncthreads();
#pragma unroll
        for (int dl = 0; dl < DC; ++dl) {
            float xf[8], cf[8];
            // x-frag: same address across wave -> broadcast (free)
            *(float4*)&xf[0] = *(const float4*)&xT[ch * DC + dl][wave * 8];
            *(float4*)&xf[4] = *(const float4*)&xT[ch * DC + dl][wave * 8 + 4];
            // c-frag: 48B lane stride -> each 16-lane phase hits every bank 2x
            // (= b128 minimum, conflict-free)
            *(float4*)&cf[0] = *(const float4*)&cT[dl][lane][0];
            *(float4*)&cf[4] = *(const float4*)&cT[dl][lane][4];
#pragma unroll
            for (int r = 0; r < 8; ++r)
#pragma unroll
                for (int k = 0; k < 8; ++k)
                    acc[r][k] = fmaf(xf[r], cf[k], acc[r][k]);
        }
        __syncthreads();
    }

    // dist + argmin. Thread's codes: lane*8+k (ascending within thread & lane).
    float c2f[8];
    *(float4*)&c2f[0] = *(const float4*)&c2s[lane * 8];
    *(float4*)&c2f[4] = *(const float4*)&c2s[lane * 8 + 4];
#pragma unroll
    for (int r = 0; r < 8; ++r) {
        float x2v = x2s[wave * 8 + r];
        float bd = __builtin_inff();
        int bk = 0;
#pragma unroll
        for (int k = 0; k < 8; ++k) {
            // reference op order: (x2 - 2*xc) + c2[k]; strict '<' ascending k
            float dist = (x2v - 2.0f * acc[r][k]) + c2f[k];
            if (dist < bd) { bd = dist; bk = lane * 8 + k; }
        }
        // cross-lane min-reduce. On EXACT float ties pick the lower code index
        // (jnp.argmin first-min). Index tie-break required: the tree reduce
        // does not preserve ascending-code visit order (R9 bug).
#pragma unroll
        for (int off = 32; off > 0; off >>= 1) {
            float od = __shfl_down(bd, off);
            int oi = __shfl_down(bk, off);
            if (od < bd || (od == bd && oi < bk)) { bd = od; bk = oi; }
        }
        if (lane == 0) sbi[wave * 8 + r] = bk;
    }
    __syncthreads();

    // output epilogue: wave w -> rows [8w, 8w+8); fully coalesced
    float lsum = 0.f;
#pragma unroll
    for (int rr = 0; rr < 8; ++rr) {
        int r = wave * 8 + rr;
        size_t grow = R0 + r;
        int bi = sbi[r];  // wave-uniform
        float xd = latents[grow * CODE_DIM + lane];   // L2/L3-hot re-read
        float qd = cb[(size_t)bi * CODE_DIM + lane];
        float e = xd - qd;
        lsum = fmaf(e, e, lsum);
        out_q[grow * CODE_DIM + lane] = xd + (qd - xd);  // reference op order
        if (lane == 0) out_codes[grow] = (float)bi;
    }
#pragma unroll
    for (int off = 32; off > 0; off >>= 1) lsum += __shfl_down(lsum, off);
    if (lane == 0) red[wave] = lsum;
    __syncthreads();
    if (tid == 0) atomicAdd(loss_accum, red[0] + red[1] + red[2] + red[3]);
}

__global__ void vq_finalize(const float* __restrict__ acc,
                            float* __restrict__ out_loss) {
    *out_loss = 1.25f * (*acc) / (float)(N_ROWS * CODE_DIM);
}

extern "C" void kernel_launch(void* const* d_in, const int* in_sizes, int n_in,
                              void* d_out, int out_size, void* d_ws, size_t ws_size,
                              hipStream_t stream) {
    const float* latents = (const float*)d_in[0];
    const float* cb      = (const float*)d_in[1];

    float* out_q     = (float*)d_out;                      // 8388608 floats
    float* out_codes = out_q + (size_t)N_ROWS * CODE_DIM;  // 131072 floats
    float* out_loss  = out_codes + N_ROWS;                 // 1 float

    float* c2  = (float*)d_ws;                             // 512 floats
    float* acc = c2 + NUM_CODES;                           // 1 float

    hipMemsetAsync(acc, 0, sizeof(float), stream);
    vq_prep<<<NUM_CODES / 64, 64, 0, stream>>>(cb, c2);
    vq_main<<<N_ROWS / RPB, 256, 0, stream>>>(latents, cb, c2, out_q,
                                              out_codes, acc);
    vq_finalize<<<1, 1, 0, stream>>>(acc, out_loss);
}